// Round 8
// baseline (27.750 us; speedup 1.0000x reference)
//
#include <hip/hip_runtime.h>
#include <hip/hip_bf16.h>

// Problem constants (match reference)
#define BQ 4096
#define KN 64
#define KH 32   // k's per wave (query split across 2 waves)
#define LD 256

__global__ __launch_bounds__(256, 4) void knn_weighted_gather_kernel(
    const float* __restrict__ sq_dists,       // [B, K]
    const int*   __restrict__ labels,         // [B, K]
    const float* __restrict__ exemplar_labels,// [N, L]
    const float* __restrict__ exemplar_sizes, // [N]
    const float* __restrict__ average_label,  // [L]
    const float* __restrict__ tau_squared_p,  // [1]
    const float* __restrict__ gamma_n_p,      // [1]
    float* __restrict__ out)                  // [B, L] f32
{
    __shared__ float4 s_acc[2][64];
    __shared__ float  s_den[2];

    const int wave = threadIdx.x >> 6;   // 0..3
    const int lane = threadIdx.x & 63;
    const int qloc = wave >> 1;          // query within block
    const int h    = wave & 1;           // k-half within query
    const int q    = blockIdx.x * 2 + qloc;

    const float tau2    = tau_squared_p[0];
    const float gamma_n = gamma_n_p[0];

    // Hoist the epilogue leaf load into the prologue.
    const float4 avg = *reinterpret_cast<const float4*>(average_label + lane * 4);

    // Lanes 0..31 own this wave's 32 k's; lanes 32..63 carry w=0, lab=0 and
    // act as safe padding targets for the branch-free 16-deep burst below.
    float w = 0.0f;
    int   lab = 0;
    if (lane < KH) {
        float d = sq_dists[q * KN + h * KH + lane];
        lab     = labels  [q * KN + h * KH + lane];
        w       = (d <= tau2) ? __expf(-d) : 0.0f;
    }

    // Partial denominator over this wave's 32 k's. FULL 64-lane butterfly
    // (off=32..1): lanes >=32 contribute exactly 0, and EVERY lane (including
    // 32..63, which write output columns 128..255 in the epilogue) ends with
    // the bitwise-identical group sum. (R7 bug: 5-step butterfly left lanes
    // >=32 with dpart=0 -> denominator halved for columns 128..255.)
    float dpart = w * exemplar_sizes[lab];
    #pragma unroll
    for (int off = 32; off > 0; off >>= 1)
        dpart += __shfl_xor(dpart, off, 64);

    // Active-k bitmask (only low 32 bits can be set). Pad with the upper 32
    // bits so a fixed 16-step walk never hits ctz(0); pad slots read lanes
    // >=32 (w=0, lab=0) -> contribute exactly 0.
    unsigned long long mask = __ballot(w != 0.0f);
    const int nact = __popcll(mask);
    mask |= 0xFFFFFFFF00000000ull;
    const int wbits = __float_as_int(w);
    const float* __restrict__ colbase = exemplar_labels + lane * 4;

    float4 acc = make_float4(0.f, 0.f, 0.f, 0.f);

#define STEP(SV, WV, LV, VV)                                          \
    int SV = (int)__builtin_ctzll(mask); mask &= mask - 1;            \
    float WV = __int_as_float(__builtin_amdgcn_readlane(wbits, SV));  \
    int LV = __builtin_amdgcn_readlane(lab, SV);                      \
    const float4 VV = *reinterpret_cast<const float4*>(colbase + (size_t)LV * LD)

#define FMA4(WV, VV)                                                  \
    acc.x += WV * VV.x; acc.y += WV * VV.y;                           \
    acc.z += WV * VV.z; acc.w += WV * VV.w

    // Single burst: issue 16 loads back-to-back, then 16 FMA groups.
    {
        STEP(s0, w0, l0, v0); STEP(s1, w1, l1, v1);
        STEP(s2, w2, l2, v2); STEP(s3, w3, l3, v3);
        STEP(s4, w4, l4, v4); STEP(s5, w5, l5, v5);
        STEP(s6, w6, l6, v6); STEP(s7, w7, l7, v7);
        STEP(s8, w8, l8, v8); STEP(s9, w9, l9, v9);
        STEP(sa, wa, la, va); STEP(sb, wb, lb, vb);
        STEP(sc, wc, lc, vc); STEP(sd, wd, ld_, vd);
        STEP(se, we, le, ve); STEP(sf, wf, lf, vf);
        FMA4(w0, v0); FMA4(w1, v1); FMA4(w2, v2); FMA4(w3, v3);
        FMA4(w4, v4); FMA4(w5, v5); FMA4(w6, v6); FMA4(w7, v7);
        FMA4(w8, v8); FMA4(w9, v9); FMA4(wa, va); FMA4(wb, vb);
        FMA4(wc, vc); FMA4(wd, vd); FMA4(we, ve); FMA4(wf, vf);
    }
    // Overflow (nact in 17..32, ~50% of waves): finish the walk.
    for (int i = 16; i < nact; ++i) {
        STEP(s0, w0, l0, v0);
        FMA4(w0, v0);
    }
#undef STEP
#undef FMA4

    // Combine the two half-query waves through LDS.
    if (h == 1) {
        s_acc[qloc][lane] = acc;
        if (lane == 0) s_den[qloc] = dpart;
    }
    __syncthreads();
    if (h == 0) {
        const float4 o = s_acc[qloc][lane];
        acc.x += o.x; acc.y += o.y; acc.z += o.z; acc.w += o.w;
        const float den = dpart + s_den[qloc] + gamma_n;
        const float inv = 1.0f / den;
        float4 res;
        res.x = (acc.x + gamma_n * avg.x) * inv;
        res.y = (acc.y + gamma_n * avg.y) * inv;
        res.z = (acc.z + gamma_n * avg.z) * inv;
        res.w = (acc.w + gamma_n * avg.w) * inv;
        *reinterpret_cast<float4*>(out + (size_t)q * LD + lane * 4) = res;
    }
}

extern "C" void kernel_launch(void* const* d_in, const int* in_sizes, int n_in,
                              void* d_out, int out_size, void* d_ws, size_t ws_size,
                              hipStream_t stream) {
    const float* sq_dists        = (const float*)d_in[0];
    const int*   labels          = (const int*)  d_in[1];
    const float* exemplar_labels = (const float*)d_in[2];
    const float* exemplar_sizes  = (const float*)d_in[3];
    const float* average_label   = (const float*)d_in[4];
    const float* tau_squared     = (const float*)d_in[5];
    const float* gamma_n         = (const float*)d_in[6];
    float* out = (float*)d_out;

    knn_weighted_gather_kernel<<<BQ / 2, 256, 0, stream>>>(
        sq_dists, labels, exemplar_labels, exemplar_sizes, average_label,
        tau_squared, gamma_n, out);
}

// Round 9
// 27.162 us; speedup vs baseline: 1.0217x; 1.0217x over previous
//
#include <hip/hip_runtime.h>
#include <hip/hip_bf16.h>

// Problem constants (match reference)
#define BQ 4096
#define KN 64
#define KH 32   // k's per wave (query split across 2 waves)
#define LD 256

// Final config (best measured: 26.82 us). One query split across 2 waves;
// lanes duplicate the 32 k's into both halves so ballot/readlane/butterfly
// see identical data; compacted active-k walk, 8-deep branch-free float4
// gather bursts; halves combined through LDS.
__global__ __launch_bounds__(256, 8) void knn_weighted_gather_kernel(
    const float* __restrict__ sq_dists,       // [B, K]
    const int*   __restrict__ labels,         // [B, K]
    const float* __restrict__ exemplar_labels,// [N, L]
    const float* __restrict__ exemplar_sizes, // [N]
    const float* __restrict__ average_label,  // [L]
    const float* __restrict__ tau_squared_p,  // [1]
    const float* __restrict__ gamma_n_p,      // [1]
    float* __restrict__ out)                  // [B, L] f32
{
    __shared__ float4 s_acc[2][64];
    __shared__ float  s_den[2];

    const int wave = threadIdx.x >> 6;   // 0..3
    const int lane = threadIdx.x & 63;
    const int qloc = wave >> 1;          // 0..1: query within block
    const int h    = wave & 1;           // 0..1: k-half within query
    const int q    = blockIdx.x * 2 + qloc;

    const float tau2    = tau_squared_p[0];
    const float gamma_n = gamma_n_p[0];

    // This wave owns k in [h*32, h*32+32). Duplicate into both 32-lane halves
    // so ballot bits 0..31, readlane, and the reduce all see the same data.
    const int kk = h * KH + (lane & (KH - 1));
    float d   = sq_dists[q * KN + kk];
    int   lab = labels  [q * KN + kk];
    float w   = (d <= tau2) ? __expf(-d) : 0.0f;

    // Partial denominator: reduce 32 distinct values within each half.
    // Both halves hold identical data -> every lane ends with the group sum.
    float dpart = w * exemplar_sizes[lab];
    #pragma unroll
    for (int off = KH / 2; off > 0; off >>= 1)
        dpart += __shfl_xor(dpart, off, 64);

    // Compact active k's: low 32 ballot bits <-> lanes 0..31 <-> this wave's k's.
    unsigned long long mask = __ballot(w != 0.0f) & 0xFFFFFFFFull;
    const int nact = __popcll(mask);
    const int wbits = __float_as_int(w);
    const float* __restrict__ colbase = exemplar_labels + lane * 4;

    float4 acc = make_float4(0.f, 0.f, 0.f, 0.f);

#define STEP(SV, WV, LV, VV)                                          \
    int SV = (int)__builtin_ctzll(mask); mask &= mask - 1;            \
    float WV = __int_as_float(__builtin_amdgcn_readlane(wbits, SV));  \
    int LV = __builtin_amdgcn_readlane(lab, SV);                      \
    const float4 VV = *reinterpret_cast<const float4*>(colbase + (size_t)LV * LD)

#define FMA4(WV, VV)                                                  \
    acc.x += WV * VV.x; acc.y += WV * VV.y;                           \
    acc.z += WV * VV.z; acc.w += WV * VV.w

    int i = 0;
    for (; i + 8 <= nact; i += 8) {
        STEP(s0, w0, l0, v0); STEP(s1, w1, l1, v1);
        STEP(s2, w2, l2, v2); STEP(s3, w3, l3, v3);
        STEP(s4, w4, l4, v4); STEP(s5, w5, l5, v5);
        STEP(s6, w6, l6, v6); STEP(s7, w7, l7, v7);
        FMA4(w0, v0); FMA4(w1, v1); FMA4(w2, v2); FMA4(w3, v3);
        FMA4(w4, v4); FMA4(w5, v5); FMA4(w6, v6); FMA4(w7, v7);
    }
    for (; i < nact; ++i) {
        STEP(s0, w0, l0, v0);
        FMA4(w0, v0);
    }
#undef STEP
#undef FMA4

    // Combine the two half-query waves through LDS.
    if (h == 1) {
        s_acc[qloc][lane] = acc;
        if (lane == 0) s_den[qloc] = dpart;
    }
    __syncthreads();
    if (h == 0) {
        const float4 o = s_acc[qloc][lane];
        acc.x += o.x; acc.y += o.y; acc.z += o.z; acc.w += o.w;
        const float den = dpart + s_den[qloc] + gamma_n;
        const float inv = 1.0f / den;
        const float4 avg = *reinterpret_cast<const float4*>(average_label + lane * 4);
        float4 res;
        res.x = (acc.x + gamma_n * avg.x) * inv;
        res.y = (acc.y + gamma_n * avg.y) * inv;
        res.z = (acc.z + gamma_n * avg.z) * inv;
        res.w = (acc.w + gamma_n * avg.w) * inv;
        *reinterpret_cast<float4*>(out + (size_t)q * LD + lane * 4) = res;
    }
}

extern "C" void kernel_launch(void* const* d_in, const int* in_sizes, int n_in,
                              void* d_out, int out_size, void* d_ws, size_t ws_size,
                              hipStream_t stream) {
    const float* sq_dists        = (const float*)d_in[0];
    const int*   labels          = (const int*)  d_in[1];
    const float* exemplar_labels = (const float*)d_in[2];
    const float* exemplar_sizes  = (const float*)d_in[3];
    const float* average_label   = (const float*)d_in[4];
    const float* tau_squared     = (const float*)d_in[5];
    const float* gamma_n         = (const float*)d_in[6];
    float* out = (float*)d_out;

    knn_weighted_gather_kernel<<<BQ / 2, 256, 0, stream>>>(
        sq_dists, labels, exemplar_labels, exemplar_sizes, average_label,
        tau_squared, gamma_n, out);
}